// Round 9
// baseline (237.998 us; speedup 1.0000x reference)
//
#include <hip/hip_runtime.h>
#include <hip/hip_fp16.h>

#define D_ 160
#define H_ 192
#define W_ 160
#define PLANE (H_*W_)          // 30720
#define VOL (D_*PLANE)         // 4915200 per sample (per quantity)
#define HWD (W_*D_)            // 25600: h-stride in transposed layout
#define NS 2
#define WSZ 729.0f

// B per sample: 5 quantities (I, J, I*I, J*J, I*J), each VOL fp16,
// TRANSPOSED layout [q][h][w][d]: d innermost so pass-2 reads each
// element exactly once via int4 d-octets (in-thread 9-window, no ring).

__global__ void k_zero(float* acc) {
    if (threadIdx.x < NS) acc[threadIdx.x] = 0.f;
}

// ---------------- pass 1: products + W-sum + H-sum -> fp16 B[q][h][w][d] ----
// block: 640 thr = 20 w-segs(8 wide) x 32 d;  owns (h-chunk of 4, d-block of 32)
// per h-step: compute rs[5][8] per thread, stage via LDS, store d-contiguous.
// grid: NS * 48 hchunks * 5 dblks = NS*240 blocks
__global__ __launch_bounds__(640) void k_wh(const float* __restrict__ I,
                                            const float* __restrict__ J,
                                            __half* __restrict__ B, long stride) {
    __shared__ __half LB[5][160][40];           // [q][w][dd + pad8] = 64 KB
    int b  = blockIdx.x;
    int sl = b / 240;
    int b2 = b % 240;
    int hchunk = b2 % 48;                       // fast: neighbor blocks share halo rows
    int dblk   = b2 / 48;                       // 0..4
    int tid = threadIdx.x;
    int seg = tid % 20;
    int dd  = tid / 20;                         // 0..31
    int w0 = seg * 8;
    int h0 = hchunk * 4;
    int d  = dblk * 32 + dd;
    const float* Ib = I + (long)sl * VOL + (long)d * PLANE;
    const float* Jb = J + (long)sl * VOL + (long)d * PLANE;
    __half* Bs = B + (long)sl * stride;

    float rs[5][8];
#pragma unroll
    for (int q = 0; q < 5; ++q)
#pragma unroll
        for (int k = 0; k < 8; ++k) rs[q][k] = 0.f;

    auto rowop = [&](int h, float sign) {
        if (h < 0 || h >= H_) return;
        const float* ri = Ib + (long)h * W_;
        const float* rj = Jb + (long)h * W_;
        float vI[16], vJ[16];
#pragma unroll
        for (int bq = 0; bq < 4; ++bq) {
            int f0 = w0 - 4 + 4 * bq;           // multiple of 4 -> aligned
            if (f0 >= 0 && f0 <= W_ - 4) {
                float4 a = *reinterpret_cast<const float4*>(ri + f0);
                float4 c = *reinterpret_cast<const float4*>(rj + f0);
                vI[4*bq+0]=a.x; vI[4*bq+1]=a.y; vI[4*bq+2]=a.z; vI[4*bq+3]=a.w;
                vJ[4*bq+0]=c.x; vJ[4*bq+1]=c.y; vJ[4*bq+2]=c.z; vJ[4*bq+3]=c.w;
            } else {
#pragma unroll
                for (int k = 0; k < 4; ++k) { vI[4*bq+k] = 0.f; vJ[4*bq+k] = 0.f; }
            }
        }
#pragma unroll
        for (int q = 0; q < 5; ++q) {
            float p[16];
#pragma unroll
            for (int i = 0; i < 16; ++i) {
                float a = vI[i], bb = vJ[i];
                p[i] = (q == 0) ? a : (q == 1) ? bb : (q == 2) ? a*a : (q == 3) ? bb*bb : a*bb;
            }
            float o[8];
            float ssum = 0.f;
#pragma unroll
            for (int i = 0; i < 9; ++i) ssum += p[i];
            o[0] = ssum;
#pragma unroll
            for (int k = 1; k < 8; ++k) { ssum += p[k + 8] - p[k - 1]; o[k] = ssum; }
#pragma unroll
            for (int k = 0; k < 8; ++k) rs[q][k] += sign * o[k];
        }
    };

    // init window rows [h0-4, h0+3]
    for (int i = 0; i < 8; ++i) rowop(h0 - 4 + i, 1.f);

    for (int hh = 0; hh < 4; ++hh) {
        int h = h0 + hh;
        rowop(h + 4, 1.f);                      // window [h-4, h+4]
#pragma unroll
        for (int q = 0; q < 5; ++q)
#pragma unroll
            for (int k = 0; k < 8; ++k) LB[q][w0 + k][dd] = __float2half(rs[q][k]);
        __syncthreads();
        // store phase: 800 (q,w) chunks, each 32 d-halves = 64 B contiguous
        for (int i = tid; i < 800; i += 640) {
            int q = i / 160, w = i % 160;
            const __half* src = &LB[q][w][0];
            __half* dst = Bs + (long)q * VOL + (long)h * HWD + (long)w * D_ + dblk * 32;
            int4 v0 = *reinterpret_cast<const int4*>(src);
            int4 v1 = *reinterpret_cast<const int4*>(src + 8);
            int4 v2 = *reinterpret_cast<const int4*>(src + 16);
            int4 v3 = *reinterpret_cast<const int4*>(src + 24);
            *reinterpret_cast<int4*>(dst)      = v0;
            *reinterpret_cast<int4*>(dst + 8)  = v1;
            *reinterpret_cast<int4*>(dst + 16) = v2;
            *reinterpret_cast<int4*>(dst + 24) = v3;
        }
        __syncthreads();
        rowop(h - 4, -1.f);                     // prep next: [h-3, h+4]
    }
}

// ---------------- pass 2: D-axis 9-box-sum + cc + reduction ----------------
// thread owns ONE (h,w), d-chunk of 40 (5 output octets). Loads int4 =
// 8 consecutive d; window from 3 named octets P/C/N (static rotation).
// Each B element read once (+2/7 halo). per sample: 160*192*4 = 122880
// threads = 480 blocks.
__device__ __forceinline__ float ccf(float Is, float Js, float I2, float J2, float IJ) {
    float uI = Is * (1.f / WSZ), uJ = Js * (1.f / WSZ);
    float cross = IJ - uJ * Is - uI * Js + uI * uJ * WSZ;
    float Iv = I2 - 2.f * uI * Is + uI * uI * WSZ;
    float Jv = J2 - 2.f * uJ * Js + uJ * uJ * WSZ;
    return 1.f - cross * cross / (Iv * Jv + 1e-5f);
}

__global__ __launch_bounds__(256) void k_d(const __half* __restrict__ B,
                                           float* __restrict__ acc, long stride) {
    int b  = blockIdx.x;
    int sl = b / 480;
    int t  = (b % 480) * 256 + threadIdx.x;     // 0..122879
    int w = t % 160;                            // lane-fast
    int h = (t / 160) % 192;
    int chunk = t / 30720;                      // 0..3
    int o0 = chunk * 5;                         // output octets o0..o0+4
    const __half* Bb = B + (long)sl * stride + (long)h * HWD + (long)w * D_;

    int4 z; z.x = z.y = z.z = z.w = 0;
    auto ld = [&](int q, int o) -> int4 {
        if (o < 0 || o >= 20) return z;
        return *reinterpret_cast<const int4*>(Bb + (long)q * VOL + o * 8);
    };

    int4 P[5], C[5], N[5];
#pragma unroll
    for (int q = 0; q < 5; ++q) { C[q] = ld(q, o0 - 1); N[q] = ld(q, o0); }

    float local = 0.f;
    for (int o = o0; o < o0 + 5; ++o) {
#pragma unroll
        for (int q = 0; q < 5; ++q) { P[q] = C[q]; C[q] = N[q]; N[q] = ld(q, o + 1); }
        float ws[5][8];
#pragma unroll
        for (int q = 0; q < 5; ++q) {
            float a[24];
            union { int4 v; __half hv[8]; } u;
            u.v = P[q];
#pragma unroll
            for (int k = 0; k < 8; ++k) a[k] = __half2float(u.hv[k]);
            u.v = C[q];
#pragma unroll
            for (int k = 0; k < 8; ++k) a[8 + k] = __half2float(u.hv[k]);
            u.v = N[q];
#pragma unroll
            for (int k = 0; k < 8; ++k) a[16 + k] = __half2float(u.hv[k]);
            // output d = 8*o + j; taps a[j+4 .. j+12]
            float s0 = 0.f;
#pragma unroll
            for (int i = 4; i <= 12; ++i) s0 += a[i];
            ws[q][0] = s0;
#pragma unroll
            for (int j = 1; j < 8; ++j) { s0 += a[j + 12] - a[j + 3]; ws[q][j] = s0; }
        }
#pragma unroll
        for (int j = 0; j < 8; ++j)
            local += ccf(ws[0][j], ws[1][j], ws[2][j], ws[3][j], ws[4][j]);
    }

    __shared__ float red[256];
    red[threadIdx.x] = local;
    __syncthreads();
    for (int off = 128; off > 0; off >>= 1) {
        if (threadIdx.x < off) red[threadIdx.x] += red[threadIdx.x + off];
        __syncthreads();
    }
    if (threadIdx.x == 0) atomicAdd(acc + sl, red[0]);
}

__global__ void k_fin(const float* __restrict__ acc, float* __restrict__ out) {
    if (threadIdx.x < NS) out[threadIdx.x] = acc[threadIdx.x] * (1.f / (float)VOL);
}

extern "C" void kernel_launch(void* const* d_in, const int* in_sizes, int n_in,
                              void* d_out, int out_size, void* d_ws, size_t ws_size,
                              hipStream_t stream) {
    const float* J = (const float*)d_in[0];   // y_pred
    const float* I = (const float*)d_in[1];   // y_true
    float* out = (float*)d_out;
    __half* B  = (__half*)d_ws;               // 2 samples x 5*VOL fp16 = 98.3 MB

    const long SAMP = 5L * VOL;
    float* acc = (float*)((char*)d_ws + (size_t)(NS * SAMP) * sizeof(__half));

    k_zero<<<1, 64, 0, stream>>>(acc);
    k_wh<<<NS * 240, 640, 0, stream>>>(I, J, B, SAMP);
    k_d<<<NS * 480, 256, 0, stream>>>(B, acc, SAMP);
    k_fin<<<1, 64, 0, stream>>>(acc, out);
}

// Round 10
// 128.440 us; speedup vs baseline: 1.8530x; 1.8530x over previous
//
#include <hip/hip_runtime.h>
#include <hip/hip_fp16.h>

#define D_ 160
#define H_ 192
#define W_ 160
#define PLANE (H_*W_)          // 30720
#define VOL (D_*PLANE)         // 4915200 per sample (per quantity)
#define NS 2
#define WSZ 729.0f
#define DC 10                  // d-outputs per k_d thread

// B per sample: 5 quantities (I, J, I*I, J*J, I*J), each VOL fp16,
// layout [q][d][h][w] (k_d threads re-read d-planes -> L2 reuse)

__global__ void k_zero(float* acc) {
    if (threadIdx.x < NS) acc[threadIdx.x] = 0.f;
}

// ---------------- pass 1: products + W-sum + H-sum -> fp16 B ----------------
// thread: 4 w (seg) x 6 h-outputs (chunk) x fixed d.  (r8 structure, hc 8->6)
// per sample: seg(40) x chunk(32) x d(160) = 204800 threads = 800 blocks.
// grid 1600, XCD-swizzled so halo-sharing neighbors are co-XCD.
__global__ __launch_bounds__(256) void k_wh(const float* __restrict__ I,
                                            const float* __restrict__ J,
                                            __half* __restrict__ B, long stride) {
    int orig = blockIdx.x;                      // 1600 blocks, 1600%8==0
    int b = (orig & 7) * 200 + (orig >> 3);     // XCD k <- contiguous [200k,200k+200)
    int sl = b / 800;
    int t  = (b % 800) * 256 + threadIdx.x;     // 0..204799
    int seg   = t % 40;
    int chunk = (t / 40) % 32;
    int d     = t / 1280;                       // 0..159
    int w0 = seg * 4;
    int h0 = chunk * 6;
    const float* Ib = I + (long)sl * VOL + (long)d * PLANE;
    const float* Jb = J + (long)sl * VOL + (long)d * PLANE;
    __half* Bb = B + (long)sl * stride + (long)d * PLANE + w0;   // + q*VOL + h*W_

    float rs[5][4];
#pragma unroll
    for (int q = 0; q < 5; ++q)
#pragma unroll
        for (int k = 0; k < 4; ++k) rs[q][k] = 0.f;

    // one row's W-window sums (4 outputs) for all 5 quantities, signed accumulate
    auto rowop = [&](int h, float sign) {
        if (h < 0 || h >= H_) return;
        const float* ri = Ib + (long)h * W_;
        const float* rj = Jb + (long)h * W_;
        float vI[12], vJ[12];
#pragma unroll
        for (int bq = 0; bq < 3; ++bq) {
            int f0 = w0 - 4 + 4 * bq;           // multiple of 4 -> aligned
            if (f0 >= 0 && f0 <= W_ - 4) {
                float4 a = *reinterpret_cast<const float4*>(ri + f0);
                float4 c = *reinterpret_cast<const float4*>(rj + f0);
                vI[4*bq+0]=a.x; vI[4*bq+1]=a.y; vI[4*bq+2]=a.z; vI[4*bq+3]=a.w;
                vJ[4*bq+0]=c.x; vJ[4*bq+1]=c.y; vJ[4*bq+2]=c.z; vJ[4*bq+3]=c.w;
            } else {
#pragma unroll
                for (int k = 0; k < 4; ++k) { vI[4*bq+k] = 0.f; vJ[4*bq+k] = 0.f; }
            }
        }
#pragma unroll
        for (int q = 0; q < 5; ++q) {
            float p[12];
#pragma unroll
            for (int i = 0; i < 12; ++i) {
                float a = vI[i], bb = vJ[i];
                p[i] = (q == 0) ? a : (q == 1) ? bb : (q == 2) ? a*a : (q == 3) ? bb*bb : a*bb;
            }
            float o[4];
            float ssum = 0.f;
#pragma unroll
            for (int i = 0; i < 9; ++i) ssum += p[i];
            o[0] = ssum;
#pragma unroll
            for (int k = 1; k < 4; ++k) { ssum += p[k + 8] - p[k - 1]; o[k] = ssum; }
#pragma unroll
            for (int k = 0; k < 4; ++k) rs[q][k] += sign * o[k];
        }
    };

    // init window rows [h0-4, h0+3]
    for (int i = 0; i < 8; ++i) rowop(h0 - 4 + i, 1.f);

    for (int hh = 0; hh < 6; ++hh) {
        int h = h0 + hh;
        rowop(h + 4, 1.f);                       // window now [h-4, h+4]
#pragma unroll
        for (int q = 0; q < 5; ++q) {
            union { __half hv[4]; uint2 v; } u;
#pragma unroll
            for (int k = 0; k < 4; ++k) u.hv[k] = __float2half(rs[q][k]);
            *reinterpret_cast<uint2*>(Bb + (long)q * VOL + (long)h * W_) = u.v;  // 8B store
        }
        rowop(h - 4, -1.f);                      // prep next: [h-3, h+4]
    }
}

// ---------------- pass 2: D-axis 9-box-sum + cc + reduction ----------------
// r4 kernel verbatim: thread = 8 consecutive w (int4 loads), fixed h, DC=10.
// Slide via add(d+5)/sub(d-4) re-loads (L2-hot, exact cancellation).
// per sample: ws(20) x h(192) x chunk(16) = 61440 threads = 240 blocks
__device__ __forceinline__ float ccf(float Is, float Js, float I2, float J2, float IJ) {
    float uI = Is * (1.f / WSZ), uJ = Js * (1.f / WSZ);
    float cross = IJ - uJ * Is - uI * Js + uI * uJ * WSZ;
    float Iv = I2 - 2.f * uI * Is + uI * uI * WSZ;
    float Jv = J2 - 2.f * uJ * Js + uJ * uJ * WSZ;
    return 1.f - cross * cross / (Iv * Jv + 1e-5f);
}

__global__ __launch_bounds__(256) void k_d(const __half* __restrict__ B,
                                           float* __restrict__ acc, long stride) {
    int b  = blockIdx.x;
    int sl = b / 240;
    int t  = (b % 240) * 256 + threadIdx.x;     // 0..61439
    int ws    = t % 20;
    int h     = (t / 20) % 192;
    int chunk = t / 3840;                       // 0..15
    int d0 = chunk * DC;
    const __half* Bb = B + (long)sl * stride + (long)h * W_ + ws * 8;  // + q*VOL + d*PLANE

    float s[5][8];
#pragma unroll
    for (int q = 0; q < 5; ++q)
#pragma unroll
        for (int k = 0; k < 8; ++k) s[q][k] = 0.f;

    auto plane = [&](float (&sq)[8], int q, int d, float sign) {
        if (d < 0 || d >= D_) return;
        union { __half hv[8]; int4 v; } u;
        u.v = *reinterpret_cast<const int4*>(Bb + (long)q * VOL + (long)d * PLANE);
#pragma unroll
        for (int k = 0; k < 8; ++k) sq[k] += sign * __half2float(u.hv[k]);
    };

    // init window [d0-4, d0+4]
#pragma unroll
    for (int q = 0; q < 5; ++q)
#pragma unroll
        for (int i = -4; i <= 4; ++i) plane(s[q], q, d0 + i, 1.f);

    float local = 0.f;
    for (int dd = 0; dd < DC; ++dd) {
#pragma unroll
        for (int k = 0; k < 8; ++k)
            local += ccf(s[0][k], s[1][k], s[2][k], s[3][k], s[4][k]);
        int da = d0 + dd + 5, dsu = d0 + dd - 4;
#pragma unroll
        for (int q = 0; q < 5; ++q) { plane(s[q], q, da, 1.f); plane(s[q], q, dsu, -1.f); }
    }

    __shared__ float red[256];
    red[threadIdx.x] = local;
    __syncthreads();
    for (int off = 128; off > 0; off >>= 1) {
        if (threadIdx.x < off) red[threadIdx.x] += red[threadIdx.x + off];
        __syncthreads();
    }
    if (threadIdx.x == 0) atomicAdd(acc + sl, red[0]);
}

__global__ void k_fin(const float* __restrict__ acc, float* __restrict__ out) {
    if (threadIdx.x < NS) out[threadIdx.x] = acc[threadIdx.x] * (1.f / (float)VOL);
}

extern "C" void kernel_launch(void* const* d_in, const int* in_sizes, int n_in,
                              void* d_out, int out_size, void* d_ws, size_t ws_size,
                              hipStream_t stream) {
    const float* J = (const float*)d_in[0];   // y_pred
    const float* I = (const float*)d_in[1];   // y_true
    float* out = (float*)d_out;
    __half* B  = (__half*)d_ws;               // 2 samples x 5*VOL fp16 = 98.3 MB

    const long SAMP = 5L * VOL;
    float* acc = (float*)((char*)d_ws + (size_t)(NS * SAMP) * sizeof(__half));

    k_zero<<<1, 64, 0, stream>>>(acc);
    k_wh<<<1600, 256, 0, stream>>>(I, J, B, SAMP);
    k_d<<<NS * 240, 256, 0, stream>>>(B, acc, SAMP);
    k_fin<<<1, 64, 0, stream>>>(acc, out);
}

// Round 11
// 117.149 us; speedup vs baseline: 2.0316x; 1.0964x over previous
//
#include <hip/hip_runtime.h>
#include <hip/hip_fp16.h>

#define D_ 160
#define H_ 192
#define W_ 160
#define PLANE (H_*W_)          // 30720
#define VOL (D_*PLANE)         // 4915200 per sample (per quantity)
#define NS 2
#define WSZ 729.0f
#define DC 8                   // d-outputs per k_d thread (10->8: +25% waves, +8% reads)

// B per sample: 5 quantities (I, J, I*I, J*J, I*J), each VOL fp16,
// layout [q][d][h][w] (k_d threads re-read d-planes -> L2/L3 reuse)

__global__ void k_zero(float* acc) {
    if (threadIdx.x < NS) acc[threadIdx.x] = 0.f;
}

// ---------------- pass 1: products + W-sum + H-sum -> fp16 B ----------------
// r8 structure verbatim (proven 65.5 us, FETCH ~= compulsory):
// thread: 4 w (seg) x 8 h-outputs (chunk) x fixed d.
// per sample: seg(40) x chunk(24) x d(160) = 153600 threads = 600 blocks
__global__ __launch_bounds__(256) void k_wh(const float* __restrict__ I,
                                            const float* __restrict__ J,
                                            __half* __restrict__ B, long stride) {
    int b  = blockIdx.x;
    int sl = b / 600;
    int t  = (b % 600) * 256 + threadIdx.x;     // 0..153599
    int seg   = t % 40;
    int chunk = (t / 40) % 24;
    int d     = t / 960;                        // 0..159
    int w0 = seg * 4;
    int h0 = chunk * 8;
    const float* Ib = I + (long)sl * VOL + (long)d * PLANE;
    const float* Jb = J + (long)sl * VOL + (long)d * PLANE;
    __half* Bb = B + (long)sl * stride + (long)d * PLANE + w0;   // + q*VOL + h*W_

    float rs[5][4];
#pragma unroll
    for (int q = 0; q < 5; ++q)
#pragma unroll
        for (int k = 0; k < 4; ++k) rs[q][k] = 0.f;

    // one row's W-window sums (4 outputs) for all 5 quantities, signed accumulate
    auto rowop = [&](int h, float sign) {
        if (h < 0 || h >= H_) return;
        const float* ri = Ib + (long)h * W_;
        const float* rj = Jb + (long)h * W_;
        float vI[12], vJ[12];
#pragma unroll
        for (int bq = 0; bq < 3; ++bq) {
            int f0 = w0 - 4 + 4 * bq;           // multiple of 4 -> aligned
            if (f0 >= 0 && f0 <= W_ - 4) {
                float4 a = *reinterpret_cast<const float4*>(ri + f0);
                float4 c = *reinterpret_cast<const float4*>(rj + f0);
                vI[4*bq+0]=a.x; vI[4*bq+1]=a.y; vI[4*bq+2]=a.z; vI[4*bq+3]=a.w;
                vJ[4*bq+0]=c.x; vJ[4*bq+1]=c.y; vJ[4*bq+2]=c.z; vJ[4*bq+3]=c.w;
            } else {
#pragma unroll
                for (int k = 0; k < 4; ++k) { vI[4*bq+k] = 0.f; vJ[4*bq+k] = 0.f; }
            }
        }
#pragma unroll
        for (int q = 0; q < 5; ++q) {
            float p[12];
#pragma unroll
            for (int i = 0; i < 12; ++i) {
                float a = vI[i], bb = vJ[i];
                p[i] = (q == 0) ? a : (q == 1) ? bb : (q == 2) ? a*a : (q == 3) ? bb*bb : a*bb;
            }
            float o[4];
            float ssum = 0.f;
#pragma unroll
            for (int i = 0; i < 9; ++i) ssum += p[i];
            o[0] = ssum;
#pragma unroll
            for (int k = 1; k < 4; ++k) { ssum += p[k + 8] - p[k - 1]; o[k] = ssum; }
#pragma unroll
            for (int k = 0; k < 4; ++k) rs[q][k] += sign * o[k];
        }
    };

    // init window rows [h0-4, h0+3]
    for (int i = 0; i < 8; ++i) rowop(h0 - 4 + i, 1.f);

    for (int hh = 0; hh < 8; ++hh) {
        int h = h0 + hh;
        rowop(h + 4, 1.f);                       // window now [h-4, h+4]
#pragma unroll
        for (int q = 0; q < 5; ++q) {
            union { __half hv[4]; uint2 v; } u;
#pragma unroll
            for (int k = 0; k < 4; ++k) u.hv[k] = __float2half(rs[q][k]);
            *reinterpret_cast<uint2*>(Bb + (long)q * VOL + (long)h * W_) = u.v;  // 8B store
        }
        rowop(h - 4, -1.f);                      // prep next: [h-3, h+4]
    }
}

// ---------------- pass 2: D-axis 9-box-sum + cc + reduction ----------------
// r4 structure (int4 8-wide loads, proven ~46 us), DC 10->8 for +25% waves.
// Slide via add(d+4)/sub(d-5) re-loads (L2/L3-hot, exact cancellation).
// per sample: ws(20) x h(192) x chunk(20) = 76800 threads = 300 blocks
__device__ __forceinline__ float ccf(float Is, float Js, float I2, float J2, float IJ) {
    float uI = Is * (1.f / WSZ), uJ = Js * (1.f / WSZ);
    float cross = IJ - uJ * Is - uI * Js + uI * uJ * WSZ;
    float Iv = I2 - 2.f * uI * Is + uI * uI * WSZ;
    float Jv = J2 - 2.f * uJ * Js + uJ * uJ * WSZ;
    return 1.f - cross * cross / (Iv * Jv + 1e-5f);
}

__global__ __launch_bounds__(256) void k_d(const __half* __restrict__ B,
                                           float* __restrict__ acc, long stride) {
    int b  = blockIdx.x;
    int sl = b / 300;
    int t  = (b % 300) * 256 + threadIdx.x;     // 0..76799
    int ws    = t % 20;
    int h     = (t / 20) % 192;
    int chunk = t / 3840;                       // 0..19
    int d0 = chunk * DC;
    const __half* Bb = B + (long)sl * stride + (long)h * W_ + ws * 8;  // + q*VOL + d*PLANE

    float s[5][8];
#pragma unroll
    for (int q = 0; q < 5; ++q)
#pragma unroll
        for (int k = 0; k < 8; ++k) s[q][k] = 0.f;

    auto plane = [&](float (&sq)[8], int q, int d, float sign) {
        if (d < 0 || d >= D_) return;
        union { __half hv[8]; int4 v; } u;
        u.v = *reinterpret_cast<const int4*>(Bb + (long)q * VOL + (long)d * PLANE);
#pragma unroll
        for (int k = 0; k < 8; ++k) sq[k] += sign * __half2float(u.hv[k]);
    };

    // init window [d0-4, d0+4]
#pragma unroll
    for (int q = 0; q < 5; ++q)
#pragma unroll
        for (int i = -4; i <= 4; ++i) plane(s[q], q, d0 + i, 1.f);

    float local = 0.f;
    for (int dd = 0; dd < DC; ++dd) {
#pragma unroll
        for (int k = 0; k < 8; ++k)
            local += ccf(s[0][k], s[1][k], s[2][k], s[3][k], s[4][k]);
        int da = d0 + dd + 5, dsu = d0 + dd - 4;
#pragma unroll
        for (int q = 0; q < 5; ++q) { plane(s[q], q, da, 1.f); plane(s[q], q, dsu, -1.f); }
    }

    __shared__ float red[256];
    red[threadIdx.x] = local;
    __syncthreads();
    for (int off = 128; off > 0; off >>= 1) {
        if (threadIdx.x < off) red[threadIdx.x] += red[threadIdx.x + off];
        __syncthreads();
    }
    if (threadIdx.x == 0) atomicAdd(acc + sl, red[0]);
}

__global__ void k_fin(const float* __restrict__ acc, float* __restrict__ out) {
    if (threadIdx.x < NS) out[threadIdx.x] = acc[threadIdx.x] * (1.f / (float)VOL);
}

extern "C" void kernel_launch(void* const* d_in, const int* in_sizes, int n_in,
                              void* d_out, int out_size, void* d_ws, size_t ws_size,
                              hipStream_t stream) {
    const float* J = (const float*)d_in[0];   // y_pred
    const float* I = (const float*)d_in[1];   // y_true
    float* out = (float*)d_out;
    __half* B  = (__half*)d_ws;               // 2 samples x 5*VOL fp16 = 98.3 MB

    const long SAMP = 5L * VOL;
    float* acc = (float*)((char*)d_ws + (size_t)(NS * SAMP) * sizeof(__half));

    k_zero<<<1, 64, 0, stream>>>(acc);
    k_wh<<<NS * 600, 256, 0, stream>>>(I, J, B, SAMP);
    k_d<<<NS * 300, 256, 0, stream>>>(B, acc, SAMP);
    k_fin<<<1, 64, 0, stream>>>(acc, out);
}

// Round 12
// 93.768 us; speedup vs baseline: 2.5381x; 1.2493x over previous
//
#include <hip/hip_runtime.h>
#include <hip/hip_fp16.h>

#define D_ 160
#define H_ 192
#define W_ 160
#define PLANE (H_*W_)          // 30720
#define VOL (D_*PLANE)         // 4915200 per sample (per quantity)
#define NS 2
#define WSZ 729.0f
#define DCH 40                 // d-outputs per k_d block
#define TILE 512               // halves of the (h,w) plane per k_d block

// B per sample: 5 quantities (I, J, I*I, J*J, I*J), each VOL fp16,
// layout [q][d][h][w].

__global__ void k_zero(float* acc) {
    if (threadIdx.x < NS) acc[threadIdx.x] = 0.f;
}

// ---------------- pass 1: products + W-sum + H-sum -> fp16 B ----------------
// r8 structure verbatim (proven 64-66 us, FETCH ~= compulsory):
// thread: 4 w (seg) x 8 h-outputs (chunk) x fixed d.
// per sample: seg(40) x chunk(24) x d(160) = 153600 threads = 600 blocks
__global__ __launch_bounds__(256) void k_wh(const float* __restrict__ I,
                                            const float* __restrict__ J,
                                            __half* __restrict__ B, long stride) {
    int b  = blockIdx.x;
    int sl = b / 600;
    int t  = (b % 600) * 256 + threadIdx.x;     // 0..153599
    int seg   = t % 40;
    int chunk = (t / 40) % 24;
    int d     = t / 960;                        // 0..159
    int w0 = seg * 4;
    int h0 = chunk * 8;
    const float* Ib = I + (long)sl * VOL + (long)d * PLANE;
    const float* Jb = J + (long)sl * VOL + (long)d * PLANE;
    __half* Bb = B + (long)sl * stride + (long)d * PLANE + w0;   // + q*VOL + h*W_

    float rs[5][4];
#pragma unroll
    for (int q = 0; q < 5; ++q)
#pragma unroll
        for (int k = 0; k < 4; ++k) rs[q][k] = 0.f;

    auto rowop = [&](int h, float sign) {
        if (h < 0 || h >= H_) return;
        const float* ri = Ib + (long)h * W_;
        const float* rj = Jb + (long)h * W_;
        float vI[12], vJ[12];
#pragma unroll
        for (int bq = 0; bq < 3; ++bq) {
            int f0 = w0 - 4 + 4 * bq;           // multiple of 4 -> aligned
            if (f0 >= 0 && f0 <= W_ - 4) {
                float4 a = *reinterpret_cast<const float4*>(ri + f0);
                float4 c = *reinterpret_cast<const float4*>(rj + f0);
                vI[4*bq+0]=a.x; vI[4*bq+1]=a.y; vI[4*bq+2]=a.z; vI[4*bq+3]=a.w;
                vJ[4*bq+0]=c.x; vJ[4*bq+1]=c.y; vJ[4*bq+2]=c.z; vJ[4*bq+3]=c.w;
            } else {
#pragma unroll
                for (int k = 0; k < 4; ++k) { vI[4*bq+k] = 0.f; vJ[4*bq+k] = 0.f; }
            }
        }
#pragma unroll
        for (int q = 0; q < 5; ++q) {
            float p[12];
#pragma unroll
            for (int i = 0; i < 12; ++i) {
                float a = vI[i], bb = vJ[i];
                p[i] = (q == 0) ? a : (q == 1) ? bb : (q == 2) ? a*a : (q == 3) ? bb*bb : a*bb;
            }
            float o[4];
            float ssum = 0.f;
#pragma unroll
            for (int i = 0; i < 9; ++i) ssum += p[i];
            o[0] = ssum;
#pragma unroll
            for (int k = 1; k < 4; ++k) { ssum += p[k + 8] - p[k - 1]; o[k] = ssum; }
#pragma unroll
            for (int k = 0; k < 4; ++k) rs[q][k] += sign * o[k];
        }
    };

    // init window rows [h0-4, h0+3]
    for (int i = 0; i < 8; ++i) rowop(h0 - 4 + i, 1.f);

    for (int hh = 0; hh < 8; ++hh) {
        int h = h0 + hh;
        rowop(h + 4, 1.f);                       // window now [h-4, h+4]
#pragma unroll
        for (int q = 0; q < 5; ++q) {
            union { __half hv[4]; uint2 v; } u;
#pragma unroll
            for (int k = 0; k < 4; ++k) u.hv[k] = __float2half(rs[q][k]);
            *reinterpret_cast<uint2*>(Bb + (long)q * VOL + (long)h * W_) = u.v;  // 8B store
        }
        rowop(h - 4, -1.f);                      // prep next: [h-3, h+4]
    }
}

// ---------------- pass 2: D-axis 9-box-sum via LDS ring + cc ----------------
// Block: 256 thr, (h,w)-tile of 512 halves, d-chunk of 40 (+9 halo = 1.2x reads).
// Per dp step: waves 0-3 load q=0..3 plane slices (64 int4 = 1 KB contiguous
// each), wave 0 also loads q=4; slices go into a 12-slot LDS ring. Each thread
// keeps fp32 running sums s[5][2] for 2 outputs: add new slice, subtract the
// slice from 9 steps ago out of LDS (bit-identical -> exact cancel).
// Ring depth 12 + one barrier/step is hazard-free: write(k+1) slot is at ring
// distance {1,11} from read slots {k, k-10} -- never equal; barrier bounds
// wave skew to one step.
// blocks: 2 samples x 4 chunks x 60 tiles = 480
__device__ __forceinline__ float ccf(float Is, float Js, float I2, float J2, float IJ) {
    float uI = Is * (1.f / WSZ), uJ = Js * (1.f / WSZ);
    float cross = IJ - uJ * Is - uI * Js + uI * uJ * WSZ;
    float Iv = I2 - 2.f * uI * Is + uI * uI * WSZ;
    float Jv = J2 - 2.f * uJ * Js + uJ * uJ * WSZ;
    return 1.f - cross * cross / (Iv * Jv + 1e-5f);
}

__global__ __launch_bounds__(256) void k_d(const __half* __restrict__ B,
                                           float* __restrict__ acc, long stride) {
    __shared__ __half ring[12][5][TILE];        // 61.4 KB -> 2 blocks/CU
    __shared__ float red[256];
    int b   = blockIdx.x;
    int sl  = b / 240;
    int r   = b % 240;
    int chunk = r / 60;                         // 0..3
    int tile  = r % 60;                         // fast index: neighbors stream together
    int c0 = chunk * DCH;
    long tile0 = (long)tile * TILE;
    int tid = threadIdx.x;
    int q0 = tid >> 6;                          // wave index -> quantity 0..3
    int g0 = tid & 63;
    bool two = (tid < 64);                      // wave 0 also loads q=4
    const __half* Bs = B + (long)sl * stride;

    int4 z; z.x = z.y = z.z = z.w = 0;
    auto ld = [&](int q, int g, int dp) -> int4 {
        if (dp < 0 || dp >= D_) return z;
        return *reinterpret_cast<const int4*>(Bs + (long)q * VOL + (long)dp * PLANE + tile0 + g * 8);
    };

    float s[5][2];
#pragma unroll
    for (int q = 0; q < 5; ++q) { s[q][0] = 0.f; s[q][1] = 0.f; }

    int4 v0 = ld(q0, g0, c0 - 4);
    int4 v1 = two ? ld(4, tid, c0 - 4) : z;

    float local = 0.f;
    for (int i = 0; i < DCH + 8; ++i) {         // dp = c0-4 .. c0+43
        int dp = c0 - 4 + i;
        int slot = (dp + 16) % 12;              // dp >= -4 -> nonneg
        *reinterpret_cast<int4*>(&ring[slot][q0][g0 * 8]) = v0;
        if (two) *reinterpret_cast<int4*>(&ring[slot][4][tid * 8]) = v1;
        if (i < DCH + 7) {                      // prefetch next plane
            v0 = ld(q0, g0, dp + 1);
            if (two) v1 = ld(4, tid, dp + 1);
        }
        __syncthreads();
        int so = (dp + 7) % 12;                 // (dp-9+16)%12
        bool dosub = (dp - 9 >= c0 - 4);
#pragma unroll
        for (int q = 0; q < 5; ++q) {
            __half2 hn = *reinterpret_cast<const __half2*>(&ring[slot][q][2 * tid]);
            float2 fn = __half22float2(hn);
            s[q][0] += fn.x; s[q][1] += fn.y;
            if (dosub) {
                __half2 ho = *reinterpret_cast<const __half2*>(&ring[so][q][2 * tid]);
                float2 fo = __half22float2(ho);
                s[q][0] -= fo.x; s[q][1] -= fo.y;
            }
        }
        int dout = dp - 4;
        if (dout >= c0 && dout < c0 + DCH) {
            local += ccf(s[0][0], s[1][0], s[2][0], s[3][0], s[4][0]);
            local += ccf(s[0][1], s[1][1], s[2][1], s[3][1], s[4][1]);
        }
        // no second barrier: ring-depth-12 slot analysis makes write(k+1)
        // disjoint from any slot still being read at step k
    }

    red[tid] = local;
    __syncthreads();
    for (int off = 128; off > 0; off >>= 1) {
        if (tid < off) red[tid] += red[tid + off];
        __syncthreads();
    }
    if (tid == 0) atomicAdd(acc + sl, red[0]);
}

__global__ void k_fin(const float* __restrict__ acc, float* __restrict__ out) {
    if (threadIdx.x < NS) out[threadIdx.x] = acc[threadIdx.x] * (1.f / (float)VOL);
}

extern "C" void kernel_launch(void* const* d_in, const int* in_sizes, int n_in,
                              void* d_out, int out_size, void* d_ws, size_t ws_size,
                              hipStream_t stream) {
    const float* J = (const float*)d_in[0];   // y_pred
    const float* I = (const float*)d_in[1];   // y_true
    float* out = (float*)d_out;
    __half* B  = (__half*)d_ws;               // 2 samples x 5*VOL fp16 = 98.3 MB

    const long SAMP = 5L * VOL;
    float* acc = (float*)((char*)d_ws + (size_t)(NS * SAMP) * sizeof(__half));

    k_zero<<<1, 64, 0, stream>>>(acc);
    k_wh<<<NS * 600, 256, 0, stream>>>(I, J, B, SAMP);
    k_d<<<480, 256, 0, stream>>>(B, acc, SAMP);
    k_fin<<<1, 64, 0, stream>>>(acc, out);
}